// Round 4
// baseline (471.677 us; speedup 1.0000x reference)
//
#include <hip/hip_runtime.h>

// ---------------------------------------------------------------------------
// MORAL 2-layer GCN on MI355X — round 4.
//   r3 + : nt loads for edge streams (protect L2-resident deg/cursor/adj),
//   deg loads dst only, aggregate unroll x8 + nt adj stream,
//   colminmax also emits bf16 features so gemm1 reads half the bytes.
// ---------------------------------------------------------------------------

typedef short bf16x8 __attribute__((ext_vector_type(8)));
typedef float f32x4 __attribute__((ext_vector_type(4)));
typedef unsigned short ushort_t;

__device__ __forceinline__ unsigned encf(float f) {
  unsigned u = __float_as_uint(f);
  return (u & 0x80000000u) ? ~u : (u | 0x80000000u);
}
__device__ __forceinline__ float decf(unsigned e) {
  unsigned u = (e & 0x80000000u) ? (e ^ 0x80000000u) : ~e;
  return __uint_as_float(u);
}
__device__ __forceinline__ ushort_t f2bf(float f) {
  unsigned u = __float_as_uint(f);
  u += 0x7FFF + ((u >> 16) & 1);  // RNE
  return (ushort_t)(u >> 16);
}
__device__ __forceinline__ float bf2f(ushort_t h) {
  return __uint_as_float((unsigned)h << 16);
}

// edges may arrive as int32 or int64 (JAX x64 flag unknown). Detect on device.
__global__ void detect_kernel(const int* __restrict__ edges, int E, int* flag64) {
  if (threadIdx.x == 0 && blockIdx.x == 0) {
    int n = (2 * E < 256) ? 2 * E : 256;
    int all_odd_zero = 1;
    for (int i = 1; i < n; i += 2)
      if (edges[i] != 0) { all_odd_zero = 0; break; }
    *flag64 = all_odd_zero;
  }
}

__global__ void init_kernel(unsigned* minenc, unsigned* maxenc, int* deg, int N) {
  int i = blockIdx.x * blockDim.x + threadIdx.x;
  if (i < 128) { minenc[i] = 0xFFFFFFFFu; maxenc[i] = 0u; }
  if (i < N) deg[i] = 0;
}

// column min/max + emit bf16 copy of features (rounding matches the GEMM's
// previous in-register conversion, so accuracy is unchanged).
__global__ void colminmax_kernel(const float* __restrict__ x, unsigned* minenc,
                                 unsigned* maxenc, ushort_t* __restrict__ xb, int N) {
  int g = blockIdx.x * blockDim.x + threadIdx.x;
  int col = g & 127;
  int r0 = g >> 7;
  int nstream = (gridDim.x * blockDim.x) >> 7;
  float mn = 3.4e38f, mx = -3.4e38f;
  for (int r = r0; r < N; r += nstream) {
    float v = x[(size_t)r * 128 + col];
    mn = fminf(mn, v); mx = fmaxf(mx, v);
    xb[(size_t)r * 128 + col] = f2bf(v);
  }
  atomicMin(&minenc[col], encf(mn));
  atomicMax(&maxenc[col], encf(mx));
}

// Wt1[j][k] = bf16(s[k]*W1[k][j]); cvec[j] = sum_k mn[k]*float(Wt1[j][k])
// Wt2[j][k] = bf16(W2[k][j]); czero = 0
__global__ void prep_kernel(const unsigned* __restrict__ minenc,
                            const unsigned* __restrict__ maxenc,
                            const float* __restrict__ W1, const float* __restrict__ W2,
                            ushort_t* __restrict__ Wt1, ushort_t* __restrict__ Wt2,
                            float* __restrict__ cvec, float* __restrict__ czero) {
  __shared__ float mn_s[128], s_s[128];
  int j = threadIdx.x;
  float mn = decf(minenc[j]);
  float mx = decf(maxenc[j]);
  float denom = (mx > mn) ? (mx - mn) : 1.0f;
  mn_s[j] = mn; s_s[j] = 1.0f / denom;
  __syncthreads();
  float c = 0.f;
  for (int k = 0; k < 128; ++k) {
    float wp = s_s[k] * W1[k * 128 + j];
    ushort_t wb = f2bf(wp);
    Wt1[j * 128 + k] = wb;
    c += mn_s[k] * bf2f(wb);  // fold against the ROUNDED weight so it cancels
    Wt2[j * 128 + k] = f2bf(W2[k * 128 + j]);
  }
  cvec[j] = c;
  czero[j] = 0.f;
}

__global__ void deg_kernel(const void* __restrict__ edges, int E,
                           const int* __restrict__ flag64, int* __restrict__ deg) {
  int e = blockIdx.x * blockDim.x + threadIdx.x;
  if (e >= E) return;
  int d;
  if (*flag64) d = (int)__builtin_nontemporal_load((const long long*)edges + E + e);
  else         d = __builtin_nontemporal_load((const int*)edges + E + e);
  atomicAdd(&deg[d], 1);
}

__global__ void dinv_kernel(const int* __restrict__ deg, float* __restrict__ dinv, int N) {
  int i = blockIdx.x * blockDim.x + threadIdx.x;
  if (i < N) dinv[i] = rsqrtf((float)deg[i] + 1.0f);  // +1 = self loop
}

// ---- prefix scan: deg -> rowptr (exclusive) --------------------------------
#define SB 256

__global__ void scan1_kernel(const int* __restrict__ deg, int* __restrict__ rowptr,
                             int* __restrict__ bsum, int N) {
  __shared__ int tmp[SB];
  int i = blockIdx.x * SB + threadIdx.x;
  int v = (i < N) ? deg[i] : 0;
  tmp[threadIdx.x] = v;
  __syncthreads();
  for (int off = 1; off < SB; off <<= 1) {
    int t = (threadIdx.x >= off) ? tmp[threadIdx.x - off] : 0;
    __syncthreads();
    tmp[threadIdx.x] += t;
    __syncthreads();
  }
  if (i < N) rowptr[i] = tmp[threadIdx.x] - v;
  if (threadIdx.x == 0) bsum[blockIdx.x] = tmp[SB - 1];
}

__global__ void scan2_kernel(int* __restrict__ bsum, int nb) {
  __shared__ int tmp[SB];
  int carry = 0;
  for (int base = 0; base < nb; base += SB) {
    int i = base + threadIdx.x;
    int v = (i < nb) ? bsum[i] : 0;
    tmp[threadIdx.x] = v;
    __syncthreads();
    for (int off = 1; off < SB; off <<= 1) {
      int t = (threadIdx.x >= off) ? tmp[threadIdx.x - off] : 0;
      __syncthreads();
      tmp[threadIdx.x] += t;
      __syncthreads();
    }
    if (i < nb) bsum[i] = carry + tmp[threadIdx.x] - v;
    carry += tmp[SB - 1];
    __syncthreads();
  }
}

__global__ void scan3_kernel(int* __restrict__ rowptr, int* __restrict__ cursor,
                             const int* __restrict__ bsum, int N, int E) {
  int i = blockIdx.x * SB + threadIdx.x;
  if (i < N) {
    int v = rowptr[i] + bsum[blockIdx.x];
    rowptr[i] = v;
    cursor[i] = v;
  }
  if (i == 0) rowptr[N] = E;
}

__global__ void fill_kernel(const void* __restrict__ edges, int E,
                            const int* __restrict__ flag64,
                            int* __restrict__ cursor, int* __restrict__ adj) {
  int e = blockIdx.x * blockDim.x + threadIdx.x;
  if (e >= E) return;
  int s, d;
  if (*flag64) {
    s = (int)__builtin_nontemporal_load((const long long*)edges + e);
    d = (int)__builtin_nontemporal_load((const long long*)edges + E + e);
  } else {
    s = __builtin_nontemporal_load((const int*)edges + e);
    d = __builtin_nontemporal_load((const int*)edges + E + e);
  }
  int pos = atomicAdd(&cursor[d], 1);
  adj[pos] = s;  // cached write: with nt edge reads, adj lines stay in L2
}

// ---- MFMA GEMM: g[bf16] = (X @ Wt^T - cvec) * dinv[row] --------------------
// Wt is [128 out-cols][128 k] bf16. Block = 256 thr = 4 waves; wave w computes
// rows blk*64+16w..+15 x all 128 cols via 8 col-tiles.
__global__ __launch_bounds__(256) void gemm_mfma_kernel(
    const ushort_t* __restrict__ X, const ushort_t* __restrict__ Wtg,
    const float* __restrict__ cvec, const float* __restrict__ dinv,
    ushort_t* __restrict__ g, int N) {
  __shared__ ushort_t wt[128 * 128];  // XOR-swizzled: byte = j*256 + (k*2 ^ ((j&7)<<4))
  int t = threadIdx.x;
  for (int c = t; c < 2048; c += 256) {  // 2048 x 16B chunks
    int j = c >> 4;
    int ko = (c & 15) << 4;  // byte offset within row
    uint4 v = *(const uint4*)(Wtg + j * 128 + (ko >> 1));
    *(uint4*)((char*)wt + j * 256 + (ko ^ ((j & 7) << 4))) = v;
  }
  __syncthreads();

  int lane = t & 63, w = t >> 6;
  int lrow = lane & 15;      // A-row / B-col within fragment
  int lk = lane >> 4;        // k-group (8 bf16 each)
  int rowA = blockIdx.x * 64 + w * 16 + lrow;
  int rA = (rowA < N) ? rowA : (N - 1);

  f32x4 acc[8];
#pragma unroll
  for (int i = 0; i < 8; ++i) acc[i] = (f32x4){0.f, 0.f, 0.f, 0.f};

#pragma unroll
  for (int ks = 0; ks < 4; ++ks) {
    int k0 = ks * 32;
    bf16x8 a = *(const bf16x8*)(X + (size_t)rA * 128 + k0 + lk * 8);
    int koff = k0 * 2 + lk * 16;
#pragma unroll
    for (int tl = 0; tl < 8; ++tl) {
      int j = tl * 16 + lrow;  // output col = Wt row
      bf16x8 b = *(const bf16x8*)((const char*)wt + j * 256 + (koff ^ ((j & 7) << 4)));
      acc[tl] = __builtin_amdgcn_mfma_f32_16x16x32_bf16(a, b, acc[tl], 0, 0, 0);
    }
  }

  int robase = blockIdx.x * 64 + w * 16 + (lane >> 4) * 4;
#pragma unroll
  for (int j = 0; j < 4; ++j) {
    int row = robase + j;
    if (row < N) {
      float dv = dinv[row];
#pragma unroll
      for (int tl = 0; tl < 8; ++tl) {
        int col = tl * 16 + lrow;
        float o = (acc[tl][j] - cvec[col]) * dv;
        g[(size_t)row * 128 + col] = f2bf(o);
      }
    }
  }
}

// ---- aggregate: 2 dst nodes per wave (32 lanes x 4 cols), pull from CSR ----
// out[d] = act(dinv[d] * (g[d] + sum_{s in adj[d]} g[s]) + b)
template <int LAYER2>
__global__ __launch_bounds__(256) void aggregate_kernel(
    const int* __restrict__ rowptr, const int* __restrict__ adj,
    const ushort_t* __restrict__ g, const float* __restrict__ dinv,
    const float* __restrict__ b, void* __restrict__ out, int N) {
  int t = blockIdx.x * blockDim.x + threadIdx.x;
  int d = t >> 5;
  if (d >= N) return;
  int lc = t & 31;  // cols lc*4 .. lc*4+3
  const ushort_t* gp = g + lc * 4;
  int beg = rowptr[d], end = rowptr[d + 1];

  ushort4 sv = *(const ushort4*)(gp + (size_t)d * 128);  // self loop
  float s0 = bf2f(sv.x), s1 = bf2f(sv.y), s2 = bf2f(sv.z), s3 = bf2f(sv.w);

  int i = beg;
  for (; i + 8 <= end; i += 8) {
    int n0 = __builtin_nontemporal_load(adj + i);
    int n1 = __builtin_nontemporal_load(adj + i + 1);
    int n2 = __builtin_nontemporal_load(adj + i + 2);
    int n3 = __builtin_nontemporal_load(adj + i + 3);
    int n4 = __builtin_nontemporal_load(adj + i + 4);
    int n5 = __builtin_nontemporal_load(adj + i + 5);
    int n6 = __builtin_nontemporal_load(adj + i + 6);
    int n7 = __builtin_nontemporal_load(adj + i + 7);
    ushort4 v0 = *(const ushort4*)(gp + (size_t)n0 * 128);
    ushort4 v1 = *(const ushort4*)(gp + (size_t)n1 * 128);
    ushort4 v2 = *(const ushort4*)(gp + (size_t)n2 * 128);
    ushort4 v3 = *(const ushort4*)(gp + (size_t)n3 * 128);
    ushort4 v4 = *(const ushort4*)(gp + (size_t)n4 * 128);
    ushort4 v5 = *(const ushort4*)(gp + (size_t)n5 * 128);
    ushort4 v6 = *(const ushort4*)(gp + (size_t)n6 * 128);
    ushort4 v7 = *(const ushort4*)(gp + (size_t)n7 * 128);
    s0 += ((bf2f(v0.x) + bf2f(v1.x)) + (bf2f(v2.x) + bf2f(v3.x))) +
          ((bf2f(v4.x) + bf2f(v5.x)) + (bf2f(v6.x) + bf2f(v7.x)));
    s1 += ((bf2f(v0.y) + bf2f(v1.y)) + (bf2f(v2.y) + bf2f(v3.y))) +
          ((bf2f(v4.y) + bf2f(v5.y)) + (bf2f(v6.y) + bf2f(v7.y)));
    s2 += ((bf2f(v0.z) + bf2f(v1.z)) + (bf2f(v2.z) + bf2f(v3.z))) +
          ((bf2f(v4.z) + bf2f(v5.z)) + (bf2f(v6.z) + bf2f(v7.z)));
    s3 += ((bf2f(v0.w) + bf2f(v1.w)) + (bf2f(v2.w) + bf2f(v3.w))) +
          ((bf2f(v4.w) + bf2f(v5.w)) + (bf2f(v6.w) + bf2f(v7.w)));
  }
  for (; i < end; ++i) {
    int s = __builtin_nontemporal_load(adj + i);
    ushort4 v = *(const ushort4*)(gp + (size_t)s * 128);
    s0 += bf2f(v.x); s1 += bf2f(v.y); s2 += bf2f(v.z); s3 += bf2f(v.w);
  }

  float dv = dinv[d];
  const float4 bb = *(const float4*)&b[lc * 4];
  float o0 = dv * s0 + bb.x, o1 = dv * s1 + bb.y;
  float o2 = dv * s2 + bb.z, o3 = dv * s3 + bb.w;
  if (!LAYER2) {  // relu + bf16 store
    o0 = fmaxf(o0, 0.f); o1 = fmaxf(o1, 0.f);
    o2 = fmaxf(o2, 0.f); o3 = fmaxf(o3, 0.f);
    ushort4 ov;
    ov.x = f2bf(o0); ov.y = f2bf(o1); ov.z = f2bf(o2); ov.w = f2bf(o3);
    *(ushort4*)((ushort_t*)out + (size_t)d * 128 + lc * 4) = ov;
  } else {
    float4 ov; ov.x = o0; ov.y = o1; ov.z = o2; ov.w = o3;
    *(float4*)((float*)out + (size_t)d * 128 + lc * 4) = ov;
  }
}

extern "C" void kernel_launch(void* const* d_in, const int* in_sizes, int n_in,
                              void* d_out, int out_size, void* d_ws, size_t ws_size,
                              hipStream_t stream) {
  const float* features = (const float*)d_in[0];
  const float* W1 = (const float*)d_in[1];
  const float* b1 = (const float*)d_in[2];
  const float* W2 = (const float*)d_in[3];
  const float* b2 = (const float*)d_in[4];
  const void* edges = d_in[5];
  const int N = in_sizes[0] / 128;
  const int E = in_sizes[5] / 2;
  const int NB = (N + SB - 1) / SB;

  float* ws = (float*)d_ws;
  size_t off = 0;
  ushort_t* gbuf = (ushort_t*)(ws + off);  off += (size_t)N * 64;  // bf16 N x 128
  ushort_t* h1 = (ushort_t*)(ws + off);    off += (size_t)N * 64;  // bf16 N x 128
  ushort_t* xb = (ushort_t*)(ws + off);    off += (size_t)N * 64;  // bf16 N x 128
  int* rowptr = (int*)(ws + off);      off += N + 4;
  int* cursor = (int*)(ws + off);      off += N + 4;
  int* adj = (int*)(ws + off);         off += E;
  int* deg = (int*)(ws + off);         off += N + 4;
  float* dinv = ws + off;              off += N + 4;
  int* bsum = (int*)(ws + off);        off += NB + 4;
  unsigned* minenc = (unsigned*)(ws + off); off += 128;
  unsigned* maxenc = (unsigned*)(ws + off); off += 128;
  ushort_t* Wt1 = (ushort_t*)(ws + off);    off += 128 * 64;
  ushort_t* Wt2 = (ushort_t*)(ws + off);    off += 128 * 64;
  float* cvec = ws + off;              off += 128;
  float* czero = ws + off;             off += 128;
  int* flag64 = (int*)(ws + off);      off += 4;

  float* outf = (float*)d_out;

  // ---- graph prep ----
  detect_kernel<<<1, 1, 0, stream>>>((const int*)edges, E, flag64);
  init_kernel<<<(N + 255) / 256, 256, 0, stream>>>(minenc, maxenc, deg, N);
  colminmax_kernel<<<1024, 256, 0, stream>>>(features, minenc, maxenc, xb, N);
  deg_kernel<<<(E + 255) / 256, 256, 0, stream>>>(edges, E, flag64, deg);
  prep_kernel<<<1, 128, 0, stream>>>(minenc, maxenc, W1, W2, Wt1, Wt2, cvec, czero);
  scan1_kernel<<<NB, SB, 0, stream>>>(deg, rowptr, bsum, N);
  scan2_kernel<<<1, SB, 0, stream>>>(bsum, NB);
  scan3_kernel<<<NB, SB, 0, stream>>>(rowptr, cursor, bsum, N, E);
  dinv_kernel<<<(N + 255) / 256, 256, 0, stream>>>(deg, dinv, N);
  fill_kernel<<<(E + 255) / 256, 256, 0, stream>>>(edges, E, flag64, cursor, adj);

  // ---- layer 1 ----
  gemm_mfma_kernel<<<(N + 63) / 64, 256, 0, stream>>>(xb, Wt1, cvec, dinv, gbuf, N);
  aggregate_kernel<0><<<((size_t)N * 32 + 255) / 256, 256, 0, stream>>>(
      rowptr, adj, gbuf, dinv, b1, h1, N);

  // ---- layer 2 ----
  gemm_mfma_kernel<<<(N + 63) / 64, 256, 0, stream>>>(h1, Wt2, czero, dinv, gbuf, N);
  aggregate_kernel<1><<<((size_t)N * 32 + 255) / 256, 256, 0, stream>>>(
      rowptr, adj, gbuf, dinv, b2, outf, N);
}

// Round 5
// 425.515 us; speedup vs baseline: 1.1085x; 1.1085x over previous
//
#include <hip/hip_runtime.h>

// ---------------------------------------------------------------------------
// MORAL 2-layer GCN on MI355X — round 5.
//   Key change: XCD-local CSR fill. Each workgroup reads HW_REG_XCC_ID and
//   only writes adj entries for dsts in its XCD's 1/8 node slice, so adj
//   writes stay in that XCD's L2 and lines fill completely (kills the
//   106 MB write amplification seen in r3/r4). Per-XCD atomic chunk queue
//   partitions the edge stream among same-XCD workgroups.
//   Also reverted r4 experiments: no xb bf16 copy (gemm1 reads fp32 again),
//   plain (cached) adj loads in aggregate.
// ---------------------------------------------------------------------------

typedef short bf16x8 __attribute__((ext_vector_type(8)));
typedef float f32x4 __attribute__((ext_vector_type(4)));
typedef unsigned short ushort_t;

__device__ __forceinline__ unsigned encf(float f) {
  unsigned u = __float_as_uint(f);
  return (u & 0x80000000u) ? ~u : (u | 0x80000000u);
}
__device__ __forceinline__ float decf(unsigned e) {
  unsigned u = (e & 0x80000000u) ? (e ^ 0x80000000u) : ~e;
  return __uint_as_float(u);
}
__device__ __forceinline__ ushort_t f2bf(float f) {
  unsigned u = __float_as_uint(f);
  u += 0x7FFF + ((u >> 16) & 1);  // RNE
  return (ushort_t)(u >> 16);
}
__device__ __forceinline__ float bf2f(ushort_t h) {
  return __uint_as_float((unsigned)h << 16);
}

// edges may arrive as int32 or int64 (JAX x64 flag unknown). Detect on device.
__global__ void detect_kernel(const int* __restrict__ edges, int E, int* flag64) {
  if (threadIdx.x == 0 && blockIdx.x == 0) {
    int n = (2 * E < 256) ? 2 * E : 256;
    int all_odd_zero = 1;
    for (int i = 1; i < n; i += 2)
      if (edges[i] != 0) { all_odd_zero = 0; break; }
    *flag64 = all_odd_zero;
  }
}

__device__ __forceinline__ void load_edge(const void* edges, int E, int e,
                                          int is64, int& s, int& d) {
  if (is64) {
    const long long* p = (const long long*)edges;
    s = (int)p[e]; d = (int)p[E + e];
  } else {
    const int* p = (const int*)edges;
    s = p[e]; d = p[E + e];
  }
}

__global__ void init_kernel(unsigned* minenc, unsigned* maxenc, int* deg,
                            int* workq, int N) {
  int i = blockIdx.x * blockDim.x + threadIdx.x;
  if (i < 128) { minenc[i] = 0xFFFFFFFFu; maxenc[i] = 0u; }
  if (i < 16) workq[i] = 0;
  if (i < N) deg[i] = 0;
}

__global__ void colminmax_kernel(const float* __restrict__ x, unsigned* minenc,
                                 unsigned* maxenc, int N) {
  int g = blockIdx.x * blockDim.x + threadIdx.x;
  int col = g & 127;
  int r0 = g >> 7;
  int nstream = (gridDim.x * blockDim.x) >> 7;
  float mn = 3.4e38f, mx = -3.4e38f;
  for (int r = r0; r < N; r += nstream) {
    float v = x[(size_t)r * 128 + col];
    mn = fminf(mn, v); mx = fmaxf(mx, v);
  }
  atomicMin(&minenc[col], encf(mn));
  atomicMax(&maxenc[col], encf(mx));
}

// Wt1[j][k] = bf16(s[k]*W1[k][j]); cvec[j] = sum_k mn[k]*float(Wt1[j][k])
// Wt2[j][k] = bf16(W2[k][j]); czero = 0
__global__ void prep_kernel(const unsigned* __restrict__ minenc,
                            const unsigned* __restrict__ maxenc,
                            const float* __restrict__ W1, const float* __restrict__ W2,
                            ushort_t* __restrict__ Wt1, ushort_t* __restrict__ Wt2,
                            float* __restrict__ cvec, float* __restrict__ czero) {
  __shared__ float mn_s[128], s_s[128];
  int j = threadIdx.x;
  float mn = decf(minenc[j]);
  float mx = decf(maxenc[j]);
  float denom = (mx > mn) ? (mx - mn) : 1.0f;
  mn_s[j] = mn; s_s[j] = 1.0f / denom;
  __syncthreads();
  float c = 0.f;
  for (int k = 0; k < 128; ++k) {
    float wp = s_s[k] * W1[k * 128 + j];
    ushort_t wb = f2bf(wp);
    Wt1[j * 128 + k] = wb;
    c += mn_s[k] * bf2f(wb);  // fold against the ROUNDED weight so it cancels
    Wt2[j * 128 + k] = f2bf(W2[k * 128 + j]);
  }
  cvec[j] = c;
  czero[j] = 0.f;
}

__global__ void deg_kernel(const void* __restrict__ edges, int E,
                           const int* __restrict__ flag64, int* __restrict__ deg) {
  int e = blockIdx.x * blockDim.x + threadIdx.x;
  if (e >= E) return;
  int d;
  if (*flag64) d = (int)__builtin_nontemporal_load((const long long*)edges + E + e);
  else         d = __builtin_nontemporal_load((const int*)edges + E + e);
  atomicAdd(&deg[d], 1);
}

__global__ void dinv_kernel(const int* __restrict__ deg, float* __restrict__ dinv, int N) {
  int i = blockIdx.x * blockDim.x + threadIdx.x;
  if (i < N) dinv[i] = rsqrtf((float)deg[i] + 1.0f);  // +1 = self loop
}

// ---- prefix scan: deg -> rowptr (exclusive) --------------------------------
#define SB 256

__global__ void scan1_kernel(const int* __restrict__ deg, int* __restrict__ rowptr,
                             int* __restrict__ bsum, int N) {
  __shared__ int tmp[SB];
  int i = blockIdx.x * SB + threadIdx.x;
  int v = (i < N) ? deg[i] : 0;
  tmp[threadIdx.x] = v;
  __syncthreads();
  for (int off = 1; off < SB; off <<= 1) {
    int t = (threadIdx.x >= off) ? tmp[threadIdx.x - off] : 0;
    __syncthreads();
    tmp[threadIdx.x] += t;
    __syncthreads();
  }
  if (i < N) rowptr[i] = tmp[threadIdx.x] - v;
  if (threadIdx.x == 0) bsum[blockIdx.x] = tmp[SB - 1];
}

__global__ void scan2_kernel(int* __restrict__ bsum, int nb) {
  __shared__ int tmp[SB];
  int carry = 0;
  for (int base = 0; base < nb; base += SB) {
    int i = base + threadIdx.x;
    int v = (i < nb) ? bsum[i] : 0;
    tmp[threadIdx.x] = v;
    __syncthreads();
    for (int off = 1; off < SB; off <<= 1) {
      int t = (threadIdx.x >= off) ? tmp[threadIdx.x - off] : 0;
      __syncthreads();
      tmp[threadIdx.x] += t;
      __syncthreads();
    }
    if (i < nb) bsum[i] = carry + tmp[threadIdx.x] - v;
    carry += tmp[SB - 1];
    __syncthreads();
  }
}

__global__ void scan3_kernel(int* __restrict__ rowptr, int* __restrict__ cursor,
                             const int* __restrict__ bsum, int N, int E) {
  int i = blockIdx.x * SB + threadIdx.x;
  if (i < N) {
    int v = rowptr[i] + bsum[blockIdx.x];
    rowptr[i] = v;
    cursor[i] = v;
  }
  if (i == 0) rowptr[N] = E;
}

// ---- XCD-local CSR fill -----------------------------------------------------
// Each workgroup handles only dsts in its XCD's node slice; same-XCD
// workgroups share the edge stream via a per-XCD chunk queue. adj writes from
// one XCD then cover a 1/8 slice (~0.8 MB) that fits its private L2, so cache
// lines fill fully before writeback.
__global__ __launch_bounds__(256) void fill_kernel(
    const void* __restrict__ edges, int E, const int* __restrict__ flag64,
    int* __restrict__ cursor, int* __restrict__ adj, int* __restrict__ workq,
    int N) {
  int xcd;
  asm volatile("s_getreg_b32 %0, hwreg(HW_REG_XCC_ID)" : "=s"(xcd));
  xcd &= 7;
  const int nlo = (int)(((long long)N * xcd) >> 3);
  const int nhi = (int)(((long long)N * (xcd + 1)) >> 3);
  const int is64 = *flag64;
  const int ITER = 8;
  const int CHUNK = 256 * ITER;
  __shared__ int chunk_s;

  for (;;) {
    __syncthreads();
    if (threadIdx.x == 0) chunk_s = atomicAdd(&workq[xcd], 1);
    __syncthreads();
    long long base = (long long)chunk_s * CHUNK;
    if (base >= E) break;
#pragma unroll
    for (int i = 0; i < ITER; ++i) {
      int e = (int)base + i * 256 + threadIdx.x;
      if (e < E) {
        int s, d;
        load_edge(edges, E, e, is64, s, d);
        if (d >= nlo && d < nhi) {
          int pos = atomicAdd(&cursor[d], 1);
          adj[pos] = s;
        }
      }
    }
  }
}

// ---- MFMA GEMM: g[bf16] = (X @ Wt^T - cvec) * dinv[row] --------------------
// Wt is [128 out-cols][128 k] bf16. Block = 256 thr = 4 waves; wave w computes
// rows blk*64+16w..+15 x all 128 cols via 8 col-tiles.
template <int XBF16>
__global__ __launch_bounds__(256) void gemm_mfma_kernel(
    const void* __restrict__ Xv, const ushort_t* __restrict__ Wtg,
    const float* __restrict__ cvec, const float* __restrict__ dinv,
    ushort_t* __restrict__ g, int N) {
  __shared__ ushort_t wt[128 * 128];  // XOR-swizzled: byte = j*256 + (k*2 ^ ((j&7)<<4))
  int t = threadIdx.x;
  for (int c = t; c < 2048; c += 256) {  // 2048 x 16B chunks
    int j = c >> 4;
    int ko = (c & 15) << 4;  // byte offset within row
    uint4 v = *(const uint4*)(Wtg + j * 128 + (ko >> 1));
    *(uint4*)((char*)wt + j * 256 + (ko ^ ((j & 7) << 4))) = v;
  }
  __syncthreads();

  int lane = t & 63, w = t >> 6;
  int lrow = lane & 15;      // A-row / B-col within fragment
  int lk = lane >> 4;        // k-group (8 bf16 each)
  int rowA = blockIdx.x * 64 + w * 16 + lrow;
  int rA = (rowA < N) ? rowA : (N - 1);

  f32x4 acc[8];
#pragma unroll
  for (int i = 0; i < 8; ++i) acc[i] = (f32x4){0.f, 0.f, 0.f, 0.f};

#pragma unroll
  for (int ks = 0; ks < 4; ++ks) {
    int k0 = ks * 32;
    bf16x8 a;
    if (XBF16) {
      a = *(const bf16x8*)((const ushort_t*)Xv + (size_t)rA * 128 + k0 + lk * 8);
    } else {
      const float* xp = (const float*)Xv + (size_t)rA * 128 + k0 + lk * 8;
      float4 f0 = *(const float4*)xp;
      float4 f1 = *(const float4*)(xp + 4);
      bf16x8 tmp;
      tmp[0] = (short)f2bf(f0.x); tmp[1] = (short)f2bf(f0.y);
      tmp[2] = (short)f2bf(f0.z); tmp[3] = (short)f2bf(f0.w);
      tmp[4] = (short)f2bf(f1.x); tmp[5] = (short)f2bf(f1.y);
      tmp[6] = (short)f2bf(f1.z); tmp[7] = (short)f2bf(f1.w);
      a = tmp;
    }
    int koff = k0 * 2 + lk * 16;
#pragma unroll
    for (int tl = 0; tl < 8; ++tl) {
      int j = tl * 16 + lrow;  // output col = Wt row
      bf16x8 b = *(const bf16x8*)((const char*)wt + j * 256 + (koff ^ ((j & 7) << 4)));
      acc[tl] = __builtin_amdgcn_mfma_f32_16x16x32_bf16(a, b, acc[tl], 0, 0, 0);
    }
  }

  int robase = blockIdx.x * 64 + w * 16 + (lane >> 4) * 4;
#pragma unroll
  for (int j = 0; j < 4; ++j) {
    int row = robase + j;
    if (row < N) {
      float dv = dinv[row];
#pragma unroll
      for (int tl = 0; tl < 8; ++tl) {
        int col = tl * 16 + lrow;
        float o = (acc[tl][j] - cvec[col]) * dv;
        g[(size_t)row * 128 + col] = f2bf(o);
      }
    }
  }
}

// ---- aggregate: 2 dst nodes per wave (32 lanes x 4 cols), pull from CSR ----
// out[d] = act(dinv[d] * (g[d] + sum_{s in adj[d]} g[s]) + b)
template <int LAYER2>
__global__ __launch_bounds__(256) void aggregate_kernel(
    const int* __restrict__ rowptr, const int* __restrict__ adj,
    const ushort_t* __restrict__ g, const float* __restrict__ dinv,
    const float* __restrict__ b, void* __restrict__ out, int N) {
  int t = blockIdx.x * blockDim.x + threadIdx.x;
  int d = t >> 5;
  if (d >= N) return;
  int lc = t & 31;  // cols lc*4 .. lc*4+3
  const ushort_t* gp = g + lc * 4;
  int beg = rowptr[d], end = rowptr[d + 1];

  ushort4 sv = *(const ushort4*)(gp + (size_t)d * 128);  // self loop
  float s0 = bf2f(sv.x), s1 = bf2f(sv.y), s2 = bf2f(sv.z), s3 = bf2f(sv.w);

  int i = beg;
  for (; i + 8 <= end; i += 8) {
    int n0 = adj[i],     n1 = adj[i + 1], n2 = adj[i + 2], n3 = adj[i + 3];
    int n4 = adj[i + 4], n5 = adj[i + 5], n6 = adj[i + 6], n7 = adj[i + 7];
    ushort4 v0 = *(const ushort4*)(gp + (size_t)n0 * 128);
    ushort4 v1 = *(const ushort4*)(gp + (size_t)n1 * 128);
    ushort4 v2 = *(const ushort4*)(gp + (size_t)n2 * 128);
    ushort4 v3 = *(const ushort4*)(gp + (size_t)n3 * 128);
    ushort4 v4 = *(const ushort4*)(gp + (size_t)n4 * 128);
    ushort4 v5 = *(const ushort4*)(gp + (size_t)n5 * 128);
    ushort4 v6 = *(const ushort4*)(gp + (size_t)n6 * 128);
    ushort4 v7 = *(const ushort4*)(gp + (size_t)n7 * 128);
    s0 += ((bf2f(v0.x) + bf2f(v1.x)) + (bf2f(v2.x) + bf2f(v3.x))) +
          ((bf2f(v4.x) + bf2f(v5.x)) + (bf2f(v6.x) + bf2f(v7.x)));
    s1 += ((bf2f(v0.y) + bf2f(v1.y)) + (bf2f(v2.y) + bf2f(v3.y))) +
          ((bf2f(v4.y) + bf2f(v5.y)) + (bf2f(v6.y) + bf2f(v7.y)));
    s2 += ((bf2f(v0.z) + bf2f(v1.z)) + (bf2f(v2.z) + bf2f(v3.z))) +
          ((bf2f(v4.z) + bf2f(v5.z)) + (bf2f(v6.z) + bf2f(v7.z)));
    s3 += ((bf2f(v0.w) + bf2f(v1.w)) + (bf2f(v2.w) + bf2f(v3.w))) +
          ((bf2f(v4.w) + bf2f(v5.w)) + (bf2f(v6.w) + bf2f(v7.w)));
  }
  for (; i < end; ++i) {
    int s = adj[i];
    ushort4 v = *(const ushort4*)(gp + (size_t)s * 128);
    s0 += bf2f(v.x); s1 += bf2f(v.y); s2 += bf2f(v.z); s3 += bf2f(v.w);
  }

  float dv = dinv[d];
  const float4 bb = *(const float4*)&b[lc * 4];
  float o0 = dv * s0 + bb.x, o1 = dv * s1 + bb.y;
  float o2 = dv * s2 + bb.z, o3 = dv * s3 + bb.w;
  if (!LAYER2) {  // relu + bf16 store
    o0 = fmaxf(o0, 0.f); o1 = fmaxf(o1, 0.f);
    o2 = fmaxf(o2, 0.f); o3 = fmaxf(o3, 0.f);
    ushort4 ov;
    ov.x = f2bf(o0); ov.y = f2bf(o1); ov.z = f2bf(o2); ov.w = f2bf(o3);
    *(ushort4*)((ushort_t*)out + (size_t)d * 128 + lc * 4) = ov;
  } else {
    float4 ov; ov.x = o0; ov.y = o1; ov.z = o2; ov.w = o3;
    *(float4*)((float*)out + (size_t)d * 128 + lc * 4) = ov;
  }
}

extern "C" void kernel_launch(void* const* d_in, const int* in_sizes, int n_in,
                              void* d_out, int out_size, void* d_ws, size_t ws_size,
                              hipStream_t stream) {
  const float* features = (const float*)d_in[0];
  const float* W1 = (const float*)d_in[1];
  const float* b1 = (const float*)d_in[2];
  const float* W2 = (const float*)d_in[3];
  const float* b2 = (const float*)d_in[4];
  const void* edges = d_in[5];
  const int N = in_sizes[0] / 128;
  const int E = in_sizes[5] / 2;
  const int NB = (N + SB - 1) / SB;

  float* ws = (float*)d_ws;
  size_t off = 0;
  ushort_t* gbuf = (ushort_t*)(ws + off);  off += (size_t)N * 64;  // bf16 N x 128
  ushort_t* h1 = (ushort_t*)(ws + off);    off += (size_t)N * 64;  // bf16 N x 128
  int* rowptr = (int*)(ws + off);      off += N + 4;
  int* cursor = (int*)(ws + off);      off += N + 4;
  int* adj = (int*)(ws + off);         off += E;
  int* deg = (int*)(ws + off);         off += N + 4;
  float* dinv = ws + off;              off += N + 4;
  int* bsum = (int*)(ws + off);        off += NB + 4;
  unsigned* minenc = (unsigned*)(ws + off); off += 128;
  unsigned* maxenc = (unsigned*)(ws + off); off += 128;
  ushort_t* Wt1 = (ushort_t*)(ws + off);    off += 128 * 64;
  ushort_t* Wt2 = (ushort_t*)(ws + off);    off += 128 * 64;
  float* cvec = ws + off;              off += 128;
  float* czero = ws + off;             off += 128;
  int* flag64 = (int*)(ws + off);      off += 4;
  int* workq = (int*)(ws + off);       off += 16;

  float* outf = (float*)d_out;

  // ---- graph prep ----
  detect_kernel<<<1, 1, 0, stream>>>((const int*)edges, E, flag64);
  init_kernel<<<(N + 255) / 256, 256, 0, stream>>>(minenc, maxenc, deg, workq, N);
  colminmax_kernel<<<512, 256, 0, stream>>>(features, minenc, maxenc, N);
  deg_kernel<<<(E + 255) / 256, 256, 0, stream>>>(edges, E, flag64, deg);
  prep_kernel<<<1, 128, 0, stream>>>(minenc, maxenc, W1, W2, Wt1, Wt2, cvec, czero);
  scan1_kernel<<<NB, SB, 0, stream>>>(deg, rowptr, bsum, N);
  scan2_kernel<<<1, SB, 0, stream>>>(bsum, NB);
  scan3_kernel<<<NB, SB, 0, stream>>>(rowptr, cursor, bsum, N, E);
  dinv_kernel<<<(N + 255) / 256, 256, 0, stream>>>(deg, dinv, N);
  fill_kernel<<<1024, 256, 0, stream>>>(edges, E, flag64, cursor, adj, workq, N);

  // ---- layer 1 ----
  gemm_mfma_kernel<0><<<(N + 63) / 64, 256, 0, stream>>>(
      features, Wt1, cvec, dinv, gbuf, N);
  aggregate_kernel<0><<<((size_t)N * 32 + 255) / 256, 256, 0, stream>>>(
      rowptr, adj, gbuf, dinv, b1, h1, N);

  // ---- layer 2 ----
  gemm_mfma_kernel<1><<<(N + 63) / 64, 256, 0, stream>>>(
      h1, Wt2, czero, dinv, gbuf, N);
  aggregate_kernel<1><<<((size_t)N * 32 + 255) / 256, 256, 0, stream>>>(
      rowptr, adj, gbuf, dinv, b2, outf, N);
}